// Round 1
// baseline (296.676 us; speedup 1.0000x reference)
//
#include <hip/hip_runtime.h>
#include <hip/hip_bf16.h>
#include <stdint.h>

typedef __attribute__((ext_vector_type(8))) __bf16 bf16x8;
typedef __attribute__((ext_vector_type(8))) short  short8;
typedef __attribute__((ext_vector_type(4))) float  f32x4;

#define MFMA16(a, b, c) __builtin_amdgcn_mfma_f32_16x16x32_bf16((a), (b), (c), 0, 0, 0)

__device__ __forceinline__ unsigned short f32_bf16(float f) {
  union { float f; unsigned u; } v; v.f = f;
  unsigned r = v.u + 0x7FFFu + ((v.u >> 16) & 1u);
  return (unsigned short)(r >> 16);
}

// ---------------- fp32 -> bf16 convert ----------------
__global__ void cvt_kernel(const float* __restrict__ in, unsigned short* __restrict__ out, int n4) {
  int i = blockIdx.x * blockDim.x + threadIdx.x;
  if (i < n4) {
    float4 v = reinterpret_cast<const float4*>(in)[i];
    ushort4 o;
    o.x = f32_bf16(v.x); o.y = f32_bf16(v.y);
    o.z = f32_bf16(v.z); o.w = f32_bf16(v.w);
    reinterpret_cast<ushort4*>(out)[i] = o;
  }
}

// ---------------- bf16 GEMM, C = A * B^T ----------------
// A: [M][K] bf16, Bm: [N][K] bf16.
// MODE 0: write QKV-split bf16 ([3][B=2][H=16][S=2048][DK=64]), Q scaled by 0.125
// MODE 1: write fp32 row-major [M][N]
template <int MODE>
__global__ __launch_bounds__(256) void gemm_bt(const unsigned short* __restrict__ A,
                                               const unsigned short* __restrict__ Bm,
                                               void* __restrict__ Cout,
                                               int M, int N, int K) {
  __shared__ unsigned short As[128 * 32];
  __shared__ unsigned short Bs[128 * 32];
  const int tid  = threadIdx.x;
  const int lane = tid & 63;
  const int wid  = tid >> 6;
  const int wr   = wid >> 1, wc = wid & 1;
  const int l16  = lane & 15, lh = lane >> 4;
  const int m0   = blockIdx.y * 128;
  const int n0   = blockIdx.x * 128;

  f32x4 acc[4][4];
#pragma unroll
  for (int mi = 0; mi < 4; ++mi)
#pragma unroll
    for (int ni = 0; ni < 4; ++ni) acc[mi][ni] = 0.f;

  // staging chunks: 512 x 16B; chunk c covers row=c>>2, k-part=(c&3)*8
  const int c0 = tid, c1 = 256 + tid;
  const unsigned short* a0 = A + (size_t)(m0 + (c0 >> 2)) * K + (c0 & 3) * 8;
  const unsigned short* a1 = A + (size_t)(m0 + (c1 >> 2)) * K + (c1 & 3) * 8;
  const unsigned short* b0 = Bm + (size_t)(n0 + (c0 >> 2)) * K + (c0 & 3) * 8;
  const unsigned short* b1 = Bm + (size_t)(n0 + (c1 >> 2)) * K + (c1 & 3) * 8;

  for (int k0 = 0; k0 < K; k0 += 32) {
    short8 ra0 = *(const short8*)(a0 + k0);
    short8 ra1 = *(const short8*)(a1 + k0);
    short8 rb0 = *(const short8*)(b0 + k0);
    short8 rb1 = *(const short8*)(b1 + k0);
    __syncthreads();
    *(short8*)(As + c0 * 8) = ra0;
    *(short8*)(As + c1 * 8) = ra1;
    *(short8*)(Bs + c0 * 8) = rb0;
    *(short8*)(Bs + c1 * 8) = rb1;
    __syncthreads();
    bf16x8 af[4], bfr[4];
#pragma unroll
    for (int i = 0; i < 4; ++i) {
      af[i]  = *(const bf16x8*)(As + (wr * 64 + i * 16 + l16) * 32 + lh * 8);
      bfr[i] = *(const bf16x8*)(Bs + (wc * 64 + i * 16 + l16) * 32 + lh * 8);
    }
#pragma unroll
    for (int mi = 0; mi < 4; ++mi)
#pragma unroll
      for (int ni = 0; ni < 4; ++ni)
        acc[mi][ni] = MFMA16(af[mi], bfr[ni], acc[mi][ni]);
  }

  if (MODE == 0) {
    unsigned short* qkv = (unsigned short*)Cout;
#pragma unroll
    for (int mi = 0; mi < 4; ++mi) {
#pragma unroll
      for (int ni = 0; ni < 4; ++ni) {
#pragma unroll
        for (int r = 0; r < 4; ++r) {
          int gm = m0 + wr * 64 + mi * 16 + lh * 4 + r;
          int gn = n0 + wc * 64 + ni * 16 + l16;
          int cc = gn >> 10, rem = gn & 1023;
          int hh = rem >> 6, dk = rem & 63;
          int bb = gm >> 11, ss = gm & 2047;
          float v = acc[mi][ni][r];
          if (cc == 0) v *= 0.125f;  // fold 1/sqrt(DK) into Q (exact pow2)
          size_t idx = ((((size_t)cc * 2 + bb) * 16 + hh) * 2048 + ss) * 64 + dk;
          qkv[idx] = f32_bf16(v);
        }
      }
    }
  } else {
    float* C = (float*)Cout;
#pragma unroll
    for (int mi = 0; mi < 4; ++mi) {
#pragma unroll
      for (int ni = 0; ni < 4; ++ni) {
#pragma unroll
        for (int r = 0; r < 4; ++r) {
          int gm = m0 + wr * 64 + mi * 16 + lh * 4 + r;
          int gn = n0 + wc * 64 + ni * 16 + l16;
          C[(size_t)gm * N + gn] = acc[mi][ni][r];
        }
      }
    }
  }
}

// ---------------- causal flash attention ----------------
// Q,K,V: [B*H][S=2048][DK=64] bf16 (Q pre-scaled by 1/8). Out: [B][S][H*64] bf16.
__global__ __launch_bounds__(256) void attn_kernel(const unsigned short* __restrict__ Qg,
                                                   const unsigned short* __restrict__ Kg,
                                                   const unsigned short* __restrict__ Vg,
                                                   unsigned short* __restrict__ Og) {
  __shared__ unsigned short Ks[32 * 64];
  __shared__ unsigned short Vt[64 * 32];
  __shared__ unsigned short Pl[4][16 * 32];

  const int tid  = threadIdx.x;
  const int lane = tid & 63;
  const int w    = tid >> 6;
  const int l16  = lane & 15, lh = lane >> 4;
  const int qt   = blockIdx.x & 31;
  const int bh   = blockIdx.x >> 5;
  const int bb   = bh >> 4, hh = bh & 15;
  const int qb   = qt * 64;
  const int wqb  = qb + w * 16;  // this wave's 16 q-rows start

  const unsigned short* Qh = Qg + (size_t)bh * (2048 * 64);
  const unsigned short* Kh = Kg + (size_t)bh * (2048 * 64);
  const unsigned short* Vh = Vg + (size_t)bh * (2048 * 64);

  // Q fragments held in registers: A-layout row=lane&15, k=(lane>>4)*8
  bf16x8 qf0 = *(const bf16x8*)(Qh + (size_t)(wqb + l16) * 64 + lh * 8);
  bf16x8 qf1 = *(const bf16x8*)(Qh + (size_t)(wqb + l16) * 64 + 32 + lh * 8);

  float m[4], l[4];
  f32x4 o[4];
#pragma unroll
  for (int r = 0; r < 4; ++r) { m[r] = -__builtin_inff(); l[r] = 0.f; }
#pragma unroll
  for (int f = 0; f < 4; ++f) o[f] = 0.f;

  const int vrow = tid >> 3, vpart = tid & 7;  // V/K staging: row 0..31, 8-elem part

  for (int kv0 = 0; kv0 < qb + 64; kv0 += 32) {
    // global loads to regs (overlaps prior compute)
    short8 kreg = *(const short8*)(Kh + (size_t)(kv0 + vrow) * 64 + vpart * 8);
    short8 vreg = *(const short8*)(Vh + (size_t)(kv0 + vrow) * 64 + vpart * 8);
    __syncthreads();  // prior tile's LDS reads done
    *(short8*)(Ks + tid * 8) = kreg;  // Ks[row][part*8] row-major [32][64]
#pragma unroll
    for (int j = 0; j < 8; ++j)
      Vt[(vpart * 8 + j) * 32 + vrow] = (unsigned short)vreg[j];  // Vt[dk][kv]
    __syncthreads();

    if (kv0 <= wqb + 15) {  // wave-uniform: any unmasked element
      f32x4 s0 = 0.f, s1 = 0.f;
      {
        bf16x8 kf;
        kf = *(const bf16x8*)(Ks + (l16) * 64 + lh * 8);
        s0 = MFMA16(qf0, kf, s0);
        kf = *(const bf16x8*)(Ks + (l16) * 64 + 32 + lh * 8);
        s0 = MFMA16(qf1, kf, s0);
        kf = *(const bf16x8*)(Ks + (16 + l16) * 64 + lh * 8);
        s1 = MFMA16(qf0, kf, s1);
        kf = *(const bf16x8*)(Ks + (16 + l16) * 64 + 32 + lh * 8);
        s1 = MFMA16(qf1, kf, s1);
      }
      if (kv0 + 31 > wqb) {  // causal mask needed
#pragma unroll
        for (int r = 0; r < 4; ++r) {
          int row = wqb + lh * 4 + r;
          if (kv0 + l16 > row)      s0[r] = -__builtin_inff();
          if (kv0 + 16 + l16 > row) s1[r] = -__builtin_inff();
        }
      }
      float esc[4];
#pragma unroll
      for (int r = 0; r < 4; ++r) {
        float t = fmaxf(s0[r], s1[r]);
        t = fmaxf(t, __shfl_xor(t, 1));
        t = fmaxf(t, __shfl_xor(t, 2));
        t = fmaxf(t, __shfl_xor(t, 4));
        t = fmaxf(t, __shfl_xor(t, 8));
        float mn = fmaxf(m[r], t);
        esc[r] = __expf(m[r] - mn);
        float p0 = __expf(s0[r] - mn);
        float p1 = __expf(s1[r] - mn);
        float rs = p0 + p1;
        rs += __shfl_xor(rs, 1);
        rs += __shfl_xor(rs, 2);
        rs += __shfl_xor(rs, 4);
        rs += __shfl_xor(rs, 8);
        l[r] = l[r] * esc[r] + rs;
        m[r] = mn;
        s0[r] = p0; s1[r] = p1;
      }
#pragma unroll
      for (int f = 0; f < 4; ++f)
#pragma unroll
        for (int r = 0; r < 4; ++r) o[f][r] *= esc[r];
      // P -> LDS (C-layout) -> reload in A-layout
#pragma unroll
      for (int r = 0; r < 4; ++r) {
        Pl[w][(lh * 4 + r) * 32 + l16]      = f32_bf16(s0[r]);
        Pl[w][(lh * 4 + r) * 32 + 16 + l16] = f32_bf16(s1[r]);
      }
      bf16x8 pf = *(const bf16x8*)(&Pl[w][l16 * 32 + lh * 8]);
#pragma unroll
      for (int f = 0; f < 4; ++f) {
        bf16x8 vf = *(const bf16x8*)(Vt + (f * 16 + l16) * 32 + lh * 8);
        o[f] = MFMA16(pf, vf, o[f]);
      }
    }
  }

  // epilogue: attn_out[b][s][h*64+dk] bf16
  unsigned short* op = Og + (size_t)bb * 2048 * 1024 + (size_t)hh * 64;
#pragma unroll
  for (int f = 0; f < 4; ++f) {
#pragma unroll
    for (int r = 0; r < 4; ++r) {
      int row = wqb + lh * 4 + r;
      op[(size_t)row * 1024 + f * 16 + l16] = f32_bf16(o[f][r] / l[r]);
    }
  }
}

extern "C" void kernel_launch(void* const* d_in, const int* in_sizes, int n_in,
                              void* d_out, int out_size, void* d_ws, size_t ws_size,
                              hipStream_t stream) {
  const float* x    = (const float*)d_in[0];
  const float* Wqkv = (const float*)d_in[1];
  const float* Wout = (const float*)d_in[2];
  float* out = (float*)d_out;

  char* ws = (char*)d_ws;
  unsigned short* xb  = (unsigned short*)(ws);                              // 8 MB
  unsigned short* wqb = (unsigned short*)(ws + (size_t)8 * 1024 * 1024);    // 6 MB
  unsigned short* wob = (unsigned short*)(ws + (size_t)14 * 1024 * 1024);   // 2 MB
  unsigned short* qkv = (unsigned short*)(ws + (size_t)16 * 1024 * 1024);   // 24 MB
  unsigned short* att = (unsigned short*)(ws + (size_t)40 * 1024 * 1024);   // 8 MB

  // fp32 -> bf16 converts
  cvt_kernel<<<4096, 256, 0, stream>>>(x, xb, 4194304 / 4);
  cvt_kernel<<<3072, 256, 0, stream>>>(Wqkv, wqb, 3145728 / 4);
  cvt_kernel<<<1024, 256, 0, stream>>>(Wout, wob, 1048576 / 4);

  // QKV projection: [4096][1024] x [3072][1024]^T -> Q/K/V split
  gemm_bt<0><<<dim3(24, 32), 256, 0, stream>>>(xb, wqb, (void*)qkv, 4096, 3072, 1024);

  const unsigned short* Qp = qkv;
  const unsigned short* Kp = qkv + 4194304;
  const unsigned short* Vp = qkv + 8388608;
  attn_kernel<<<1024, 256, 0, stream>>>(Qp, Kp, Vp, att);

  // output projection: [4096][1024] x [1024][1024]^T -> fp32 out
  gemm_bt<1><<<dim3(8, 32), 256, 0, stream>>>(att, wob, (void*)out, 4096, 1024, 1024);
}

// Round 2
// 154.734 us; speedup vs baseline: 1.9173x; 1.9173x over previous
//
#include <hip/hip_runtime.h>
#include <hip/hip_bf16.h>
#include <stdint.h>

typedef __attribute__((ext_vector_type(8))) __bf16 bf16x8;
typedef __attribute__((ext_vector_type(8))) short  short8;
typedef __attribute__((ext_vector_type(4))) float  f32x4;

#define MFMA16(a, b, c) __builtin_amdgcn_mfma_f32_16x16x32_bf16((a), (b), (c), 0, 0, 0)

__device__ __forceinline__ unsigned short f32_bf16(float f) {
  union { float f; unsigned u; } v; v.f = f;
  unsigned r = v.u + 0x7FFFu + ((v.u >> 16) & 1u);
  return (unsigned short)(r >> 16);
}

// ---------------- fp32 -> bf16 convert ----------------
__global__ void cvt_kernel(const float* __restrict__ in, unsigned short* __restrict__ out, int n4) {
  int i = blockIdx.x * blockDim.x + threadIdx.x;
  if (i < n4) {
    float4 v = reinterpret_cast<const float4*>(in)[i];
    ushort4 o;
    o.x = f32_bf16(v.x); o.y = f32_bf16(v.y);
    o.z = f32_bf16(v.z); o.w = f32_bf16(v.w);
    reinterpret_cast<ushort4*>(out)[i] = o;
  }
}

// ---------------- bf16 GEMM, C = A * B^T ----------------
// MODE 0: write Q,K as [bh][s][64] bf16 (Q scaled 0.125), V transposed as [bh][64][s]
// MODE 1: write fp32 row-major [M][N]
template <int MODE>
__global__ __launch_bounds__(256) void gemm_bt(const unsigned short* __restrict__ A,
                                               const unsigned short* __restrict__ Bm,
                                               void* __restrict__ Cout,
                                               int M, int N, int K) {
  __shared__ unsigned short As[128 * 32];
  __shared__ unsigned short Bs[128 * 32];
  const int tid  = threadIdx.x;
  const int lane = tid & 63;
  const int wid  = tid >> 6;
  const int wr   = wid >> 1, wc = wid & 1;
  const int l16  = lane & 15, lh = lane >> 4;
  const int m0   = blockIdx.y * 128;
  const int n0   = blockIdx.x * 128;

  f32x4 acc[4][4];
#pragma unroll
  for (int mi = 0; mi < 4; ++mi)
#pragma unroll
    for (int ni = 0; ni < 4; ++ni) acc[mi][ni] = 0.f;

  const int c0 = tid, c1 = 256 + tid;
  const unsigned short* a0 = A + (size_t)(m0 + (c0 >> 2)) * K + (c0 & 3) * 8;
  const unsigned short* a1 = A + (size_t)(m0 + (c1 >> 2)) * K + (c1 & 3) * 8;
  const unsigned short* b0 = Bm + (size_t)(n0 + (c0 >> 2)) * K + (c0 & 3) * 8;
  const unsigned short* b1 = Bm + (size_t)(n0 + (c1 >> 2)) * K + (c1 & 3) * 8;

  for (int k0 = 0; k0 < K; k0 += 32) {
    short8 ra0 = *(const short8*)(a0 + k0);
    short8 ra1 = *(const short8*)(a1 + k0);
    short8 rb0 = *(const short8*)(b0 + k0);
    short8 rb1 = *(const short8*)(b1 + k0);
    __syncthreads();
    *(short8*)(As + c0 * 8) = ra0;
    *(short8*)(As + c1 * 8) = ra1;
    *(short8*)(Bs + c0 * 8) = rb0;
    *(short8*)(Bs + c1 * 8) = rb1;
    __syncthreads();
    bf16x8 af[4], bfr[4];
#pragma unroll
    for (int i = 0; i < 4; ++i) {
      af[i]  = *(const bf16x8*)(As + (wr * 64 + i * 16 + l16) * 32 + lh * 8);
      bfr[i] = *(const bf16x8*)(Bs + (wc * 64 + i * 16 + l16) * 32 + lh * 8);
    }
#pragma unroll
    for (int mi = 0; mi < 4; ++mi)
#pragma unroll
      for (int ni = 0; ni < 4; ++ni)
        acc[mi][ni] = MFMA16(af[mi], bfr[ni], acc[mi][ni]);
  }

  if (MODE == 0) {
    unsigned short* qkv = (unsigned short*)Cout;
#pragma unroll
    for (int mi = 0; mi < 4; ++mi) {
#pragma unroll
      for (int ni = 0; ni < 4; ++ni) {
#pragma unroll
        for (int r = 0; r < 4; ++r) {
          int gm = m0 + wr * 64 + mi * 16 + lh * 4 + r;
          int gn = n0 + wc * 64 + ni * 16 + l16;
          int cc = gn >> 10, rem = gn & 1023;
          int hh = rem >> 6, dk = rem & 63;
          int bb = gm >> 11, ss = gm & 2047;
          int bh = bb * 16 + hh;
          float v = acc[mi][ni][r];
          size_t idx;
          if (cc == 2) {
            // V transposed: [bh][dk][s]
            idx = (size_t)8388608 + ((size_t)bh * 64 + dk) * 2048 + ss;
          } else {
            if (cc == 0) v *= 0.125f;  // fold 1/sqrt(DK) into Q
            idx = (((size_t)cc * 32 + bh) * 2048 + ss) * 64 + dk;
          }
          qkv[idx] = f32_bf16(v);
        }
      }
    }
  } else {
    float* C = (float*)Cout;
#pragma unroll
    for (int mi = 0; mi < 4; ++mi) {
#pragma unroll
      for (int ni = 0; ni < 4; ++ni) {
#pragma unroll
        for (int r = 0; r < 4; ++r) {
          int gm = m0 + wr * 64 + mi * 16 + lh * 4 + r;
          int gn = n0 + wc * 64 + ni * 16 + l16;
          C[(size_t)gm * N + gn] = acc[mi][ni][r];
        }
      }
    }
  }
}

// ---------------- causal flash attention ----------------
// Q: [bh][2048][64] (prescaled by 1/8), K: [bh][2048][64], Vt: [bh][64][2048] bf16.
// Out: [B][2048][16*64] bf16. 4 waves/block, 16 q-rows/wave, KVBLK=64,
// double-buffered LDS, chunk-XOR swizzle (T2) on K/V/P tiles, 1 barrier/iter.
__global__ __launch_bounds__(256) void attn_kernel(const unsigned short* __restrict__ Qg,
                                                   const unsigned short* __restrict__ Kg,
                                                   const unsigned short* __restrict__ Vtg,
                                                   unsigned short* __restrict__ Og) {
  __shared__ unsigned short Ks[2][64 * 64];
  __shared__ unsigned short Vs[2][64 * 64];
  __shared__ unsigned short Pl[4][16 * 64];

  const int tid  = threadIdx.x;
  const int lane = tid & 63;
  const int w    = tid >> 6;
  const int l16  = lane & 15, lh = lane >> 4;
  const int qt   = 31 - (blockIdx.x >> 5);  // LPT: heaviest q-tiles first
  const int bh   = blockIdx.x & 31;
  const int bb   = bh >> 4, hh = bh & 15;
  const int qb   = qt * 64;
  const int wqb  = qb + w * 16;

  const unsigned short* Qh = Qg + (size_t)bh * (2048 * 64);
  const unsigned short* Kh = Kg + (size_t)bh * (2048 * 64);
  const unsigned short* Vh = Vtg + (size_t)bh * (64 * 2048);

  bf16x8 qf0 = *(const bf16x8*)(Qh + (size_t)(wqb + l16) * 64 + lh * 8);
  bf16x8 qf1 = *(const bf16x8*)(Qh + (size_t)(wqb + l16) * 64 + 32 + lh * 8);

  float mm[4], ll[4];
  f32x4 o[4];
#pragma unroll
  for (int r = 0; r < 4; ++r) { mm[r] = -__builtin_inff(); ll[r] = 0.f; }
#pragma unroll
  for (int f = 0; f < 4; ++f) o[f] = 0.f;

  // staging: 512 16B-chunks per 64x64 tile; thread handles chunks tid, tid+256
  const int c0 = tid, c1 = tid + 256;
  const int r0 = c0 >> 3, h0 = c0 & 7;
  const int r1 = c1 >> 3, h1 = c1 & 7;
  const int s0i = r0 * 8 + (h0 ^ (r0 & 7));  // XOR-swizzled LDS chunk slot
  const int s1i = r1 * 8 + (h1 ^ (r1 & 7));
  const int sw = l16 & 7;

  const int ntiles = qt + 1;

  {  // prologue: stage tile 0 into buffer 0
    short8 k0 = *(const short8*)(Kh + (size_t)r0 * 64 + h0 * 8);
    short8 k1 = *(const short8*)(Kh + (size_t)r1 * 64 + h1 * 8);
    short8 v0 = *(const short8*)(Vh + (size_t)r0 * 2048 + h0 * 8);
    short8 v1 = *(const short8*)(Vh + (size_t)r1 * 2048 + h1 * 8);
    *(short8*)(&Ks[0][s0i * 8]) = k0;
    *(short8*)(&Ks[0][s1i * 8]) = k1;
    *(short8*)(&Vs[0][s0i * 8]) = v0;
    *(short8*)(&Vs[0][s1i * 8]) = v1;
  }
  __syncthreads();

  for (int t = 0; t < ntiles; ++t) {
    const int kv0 = t * 64;
    const int cur = t & 1;
    const bool pfetch = (t + 1 < ntiles);
    short8 nk0, nk1, nv0, nv1;
    if (pfetch) {  // issue next tile's loads; latency hides under compute
      nk0 = *(const short8*)(Kh + (size_t)(kv0 + 64 + r0) * 64 + h0 * 8);
      nk1 = *(const short8*)(Kh + (size_t)(kv0 + 64 + r1) * 64 + h1 * 8);
      nv0 = *(const short8*)(Vh + (size_t)r0 * 2048 + kv0 + 64 + h0 * 8);
      nv1 = *(const short8*)(Vh + (size_t)r1 * 2048 + kv0 + 64 + h1 * 8);
    }

    const unsigned short* Kb = Ks[cur];
    const unsigned short* Vb = Vs[cur];

    // QK^T: S[q=lh*4+r][kv=tt*16+l16]
    f32x4 s[4];
#pragma unroll
    for (int tt = 0; tt < 4; ++tt) {
      const unsigned short* krow = Kb + (tt * 16 + l16) * 64;
      bf16x8 kf0 = *(const bf16x8*)(krow + ((lh ^ sw) * 8));
      bf16x8 kf1 = *(const bf16x8*)(krow + (((lh + 4) ^ sw) * 8));
      f32x4 a = {0.f, 0.f, 0.f, 0.f};
      a = MFMA16(qf0, kf0, a);
      a = MFMA16(qf1, kf1, a);
      s[tt] = a;
    }

    if (kv0 + 63 > wqb) {  // causal mask
#pragma unroll
      for (int tt = 0; tt < 4; ++tt) {
        int col = kv0 + tt * 16 + l16;
#pragma unroll
        for (int r = 0; r < 4; ++r)
          if (col > wqb + lh * 4 + r) s[tt][r] = -__builtin_inff();
      }
    }

    // online softmax (reduce over 4 regs + 16 lanes)
    float esc[4];
#pragma unroll
    for (int r = 0; r < 4; ++r) {
      float t0 = fmaxf(fmaxf(s[0][r], s[1][r]), fmaxf(s[2][r], s[3][r]));
      t0 = fmaxf(t0, __shfl_xor(t0, 1));
      t0 = fmaxf(t0, __shfl_xor(t0, 2));
      t0 = fmaxf(t0, __shfl_xor(t0, 4));
      t0 = fmaxf(t0, __shfl_xor(t0, 8));
      float mn = fmaxf(mm[r], t0);
      esc[r] = __expf(mm[r] - mn);
      mm[r] = mn;
      float p0 = __expf(s[0][r] - mn);
      float p1 = __expf(s[1][r] - mn);
      float p2 = __expf(s[2][r] - mn);
      float p3 = __expf(s[3][r] - mn);
      s[0][r] = p0; s[1][r] = p1; s[2][r] = p2; s[3][r] = p3;
      float rs = (p0 + p1) + (p2 + p3);
      rs += __shfl_xor(rs, 1);
      rs += __shfl_xor(rs, 2);
      rs += __shfl_xor(rs, 4);
      rs += __shfl_xor(rs, 8);
      ll[r] = ll[r] * esc[r] + rs;
    }
#pragma unroll
    for (int f = 0; f < 4; ++f)
#pragma unroll
      for (int r = 0; r < 4; ++r) o[f][r] *= esc[r];

    // P -> wave-private LDS (swizzled), reload as A-fragments
    unsigned short* Pw = Pl[w];
#pragma unroll
    for (int r = 0; r < 4; ++r) {
      int prow = lh * 4 + r;
      int pbase = prow * 64;
      int px = (prow & 7) << 3;
#pragma unroll
      for (int tt = 0; tt < 4; ++tt)
        Pw[pbase + ((tt * 16 + l16) ^ px)] = f32_bf16(s[tt][r]);
    }
    bf16x8 pf0 = *(const bf16x8*)(Pw + l16 * 64 + ((lh ^ sw) * 8));
    bf16x8 pf1 = *(const bf16x8*)(Pw + l16 * 64 + (((lh + 4) ^ sw) * 8));
#pragma unroll
    for (int f = 0; f < 4; ++f) {
      const unsigned short* vrow = Vb + (f * 16 + l16) * 64;
      bf16x8 vf0 = *(const bf16x8*)(vrow + ((lh ^ sw) * 8));
      bf16x8 vf1 = *(const bf16x8*)(vrow + (((lh + 4) ^ sw) * 8));
      o[f] = MFMA16(pf0, vf0, o[f]);
      o[f] = MFMA16(pf1, vf1, o[f]);
    }

    if (pfetch) {  // write next tile into the other buffer (vmcnt waits here)
      *(short8*)(&Ks[cur ^ 1][s0i * 8]) = nk0;
      *(short8*)(&Ks[cur ^ 1][s1i * 8]) = nk1;
      *(short8*)(&Vs[cur ^ 1][s0i * 8]) = nv0;
      *(short8*)(&Vs[cur ^ 1][s1i * 8]) = nv1;
    }
    __syncthreads();
  }

  unsigned short* op = Og + (size_t)bb * 2048 * 1024 + (size_t)hh * 64;
#pragma unroll
  for (int f = 0; f < 4; ++f) {
#pragma unroll
    for (int r = 0; r < 4; ++r) {
      int row = wqb + lh * 4 + r;
      op[(size_t)row * 1024 + f * 16 + l16] = f32_bf16(o[f][r] / ll[r]);
    }
  }
}

extern "C" void kernel_launch(void* const* d_in, const int* in_sizes, int n_in,
                              void* d_out, int out_size, void* d_ws, size_t ws_size,
                              hipStream_t stream) {
  const float* x    = (const float*)d_in[0];
  const float* Wqkv = (const float*)d_in[1];
  const float* Wout = (const float*)d_in[2];
  float* out = (float*)d_out;

  char* ws = (char*)d_ws;
  unsigned short* xb  = (unsigned short*)(ws);                              // 8 MB
  unsigned short* wqb = (unsigned short*)(ws + (size_t)8 * 1024 * 1024);    // 6 MB
  unsigned short* wob = (unsigned short*)(ws + (size_t)14 * 1024 * 1024);   // 2 MB
  unsigned short* qkv = (unsigned short*)(ws + (size_t)16 * 1024 * 1024);   // 24 MB
  unsigned short* att = (unsigned short*)(ws + (size_t)40 * 1024 * 1024);   // 8 MB

  cvt_kernel<<<4096, 256, 0, stream>>>(x, xb, 4194304 / 4);
  cvt_kernel<<<3072, 256, 0, stream>>>(Wqkv, wqb, 3145728 / 4);
  cvt_kernel<<<1024, 256, 0, stream>>>(Wout, wob, 1048576 / 4);

  // QKV projection -> Q,K [bh][s][dk]; V transposed [bh][dk][s]
  gemm_bt<0><<<dim3(24, 32), 256, 0, stream>>>(xb, wqb, (void*)qkv, 4096, 3072, 1024);

  const unsigned short* Qp  = qkv;
  const unsigned short* Kp  = qkv + 4194304;
  const unsigned short* Vtp = qkv + 8388608;
  attn_kernel<<<1024, 256, 0, stream>>>(Qp, Kp, Vtp, att);

  // output projection -> fp32 out
  gemm_bt<1><<<dim3(8, 32), 256, 0, stream>>>(att, wob, (void*)out, 4096, 1024, 1024);
}

// Round 3
// 139.966 us; speedup vs baseline: 2.1196x; 1.1055x over previous
//
#include <hip/hip_runtime.h>
#include <hip/hip_bf16.h>
#include <stdint.h>

typedef __attribute__((ext_vector_type(8))) __bf16 bf16x8;
typedef __attribute__((ext_vector_type(8))) short  short8;
typedef __attribute__((ext_vector_type(4))) float  f32x4;

#define MFMA16(a, b, c) __builtin_amdgcn_mfma_f32_16x16x32_bf16((a), (b), (c), 0, 0, 0)

__device__ __forceinline__ unsigned short f32_bf16(float f) {
  union { float f; unsigned u; } v; v.f = f;
  unsigned r = v.u + 0x7FFFu + ((v.u >> 16) & 1u);
  return (unsigned short)(r >> 16);
}

// async global->LDS, 16B per lane; LDS dest must be wave-uniform base (+lane*16 by HW)
__device__ __forceinline__ void gload16(const unsigned short* g, unsigned short* l) {
  __builtin_amdgcn_global_load_lds(
      (const __attribute__((address_space(1))) unsigned int*)(g),
      (__attribute__((address_space(3))) unsigned int*)(l), 16, 0, 0);
}

// ---------------- fp32 -> bf16 convert ----------------
__global__ void cvt_kernel(const float* __restrict__ in, unsigned short* __restrict__ out, int n4) {
  int i = blockIdx.x * blockDim.x + threadIdx.x;
  if (i < n4) {
    float4 v = reinterpret_cast<const float4*>(in)[i];
    ushort4 o;
    o.x = f32_bf16(v.x); o.y = f32_bf16(v.y);
    o.z = f32_bf16(v.z); o.w = f32_bf16(v.w);
    reinterpret_cast<ushort4*>(out)[i] = o;
  }
}

// ---------------- bf16 GEMM, C = A * B^T (m97 structure: global_load_lds) ------
// MODE 0: write Q,K as [bh][s][64] bf16 (Q scaled 0.125*log2e), V^T as [bh][64][s]
// MODE 1: write fp32 row-major [M][N]
template <int MODE>
__global__ __launch_bounds__(256) void gemm_bt(const unsigned short* __restrict__ A,
                                               const unsigned short* __restrict__ Bm,
                                               void* __restrict__ Cout,
                                               int M, int N, int K) {
  __shared__ unsigned short As[128 * 32];
  __shared__ unsigned short Bs[128 * 32];
  const int tid  = threadIdx.x;
  const int lane = tid & 63;
  const int wid  = tid >> 6;
  const int wr   = wid >> 1, wc = wid & 1;
  const int l16  = lane & 15, lh = lane >> 4;
  const int m0   = blockIdx.y * 128;
  const int n0   = blockIdx.x * 128;

  f32x4 acc[4][4];
#pragma unroll
  for (int mi = 0; mi < 4; ++mi)
#pragma unroll
    for (int ni = 0; ni < 4; ++ni) acc[mi][ni] = 0.f;

  // chunk c (16B) covers row c>>2, k-part (c&3)*8; LDS layout is linear in c
  const int c0 = tid, c1 = 256 + tid;
  const unsigned short* a0 = A + (size_t)(m0 + (c0 >> 2)) * K + (c0 & 3) * 8;
  const unsigned short* a1 = A + (size_t)(m0 + (c1 >> 2)) * K + (c1 & 3) * 8;
  const unsigned short* b0 = Bm + (size_t)(n0 + (c0 >> 2)) * K + (c0 & 3) * 8;
  const unsigned short* b1 = Bm + (size_t)(n0 + (c1 >> 2)) * K + (c1 & 3) * 8;
  const int d0 = wid * 64 * 8;            // wave-uniform LDS element offset
  const int d1 = (256 + wid * 64) * 8;

  for (int k0 = 0; k0 < K; k0 += 32) {
    __syncthreads();                      // prior tile's ds_reads done
    gload16(a0 + k0, As + d0);
    gload16(a1 + k0, As + d1);
    gload16(b0 + k0, Bs + d0);
    gload16(b1 + k0, Bs + d1);
    __syncthreads();                      // vmcnt drained by compiler
    bf16x8 af[4], bfr[4];
#pragma unroll
    for (int i = 0; i < 4; ++i) {
      af[i]  = *(const bf16x8*)(As + (wr * 64 + i * 16 + l16) * 32 + lh * 8);
      bfr[i] = *(const bf16x8*)(Bs + (wc * 64 + i * 16 + l16) * 32 + lh * 8);
    }
#pragma unroll
    for (int mi = 0; mi < 4; ++mi)
#pragma unroll
      for (int ni = 0; ni < 4; ++ni)
        acc[mi][ni] = MFMA16(af[mi], bfr[ni], acc[mi][ni]);
  }

  if (MODE == 0) {
    unsigned short* qkv = (unsigned short*)Cout;
#pragma unroll
    for (int mi = 0; mi < 4; ++mi) {
#pragma unroll
      for (int ni = 0; ni < 4; ++ni) {
#pragma unroll
        for (int r = 0; r < 4; ++r) {
          int gm = m0 + wr * 64 + mi * 16 + lh * 4 + r;
          int gn = n0 + wc * 64 + ni * 16 + l16;
          int cc = gn >> 10, rem = gn & 1023;
          int hh = rem >> 6, dk = rem & 63;
          int bb = gm >> 11, ss = gm & 2047;
          int bh = bb * 16 + hh;
          float v = acc[mi][ni][r];
          size_t idx;
          if (cc == 2) {
            idx = (size_t)8388608 + ((size_t)bh * 64 + dk) * 2048 + ss;  // V^T
          } else {
            if (cc == 0) v *= 0.18033688f;  // 1/sqrt(64) * log2(e): exp2-space scores
            idx = (((size_t)cc * 32 + bh) * 2048 + ss) * 64 + dk;
          }
          qkv[idx] = f32_bf16(v);
        }
      }
    }
  } else {
    float* C = (float*)Cout;
#pragma unroll
    for (int mi = 0; mi < 4; ++mi) {
#pragma unroll
      for (int ni = 0; ni < 4; ++ni) {
#pragma unroll
        for (int r = 0; r < 4; ++r) {
          int gm = m0 + wr * 64 + mi * 16 + lh * 4 + r;
          int gn = n0 + wc * 64 + ni * 16 + l16;
          C[(size_t)gm * N + gn] = acc[mi][ni][r];
        }
      }
    }
  }
}

// ---------------- causal flash attention ----------------
// Q: [bh][2048][64] (prescaled by log2e/8), K: [bh][2048][64], Vt: [bh][64][2048].
// exp2-space online softmax, defer-max (T13, m init 0), MFMA-computed row sums,
// global_load_lds staging with pre-swizzled source (m173), dbuf, 1 barrier/iter.
__global__ __launch_bounds__(256) void attn_kernel(const unsigned short* __restrict__ Qg,
                                                   const unsigned short* __restrict__ Kg,
                                                   const unsigned short* __restrict__ Vtg,
                                                   unsigned short* __restrict__ Og) {
  __shared__ unsigned short Ks[2][64 * 64];
  __shared__ unsigned short Vs[2][64 * 64];
  __shared__ unsigned short Pl[4][16 * 64];

  const int tid  = threadIdx.x;
  const int lane = tid & 63;
  const int w    = tid >> 6;
  const int l16  = lane & 15, lh = lane >> 4;
  const int qt   = 31 - (blockIdx.x >> 5);  // LPT: heaviest q-tiles first
  const int bh   = blockIdx.x & 31;
  const int bb   = bh >> 4, hh = bh & 15;
  const int qb   = qt * 64;
  const int wqb  = qb + w * 16;

  const unsigned short* Qh = Qg + (size_t)bh * (2048 * 64);
  const unsigned short* Kh = Kg + (size_t)bh * (2048 * 64);
  const unsigned short* Vh = Vtg + (size_t)bh * (64 * 2048);

  bf16x8 qf0 = *(const bf16x8*)(Qh + (size_t)(wqb + l16) * 64 + lh * 8);
  bf16x8 qf1 = *(const bf16x8*)(Qh + (size_t)(wqb + l16) * 64 + 32 + lh * 8);

  float mreg[4];
  f32x4 o[4], ol;
#pragma unroll
  for (int r = 0; r < 4; ++r) mreg[r] = 0.f;  // defer-max: scores ~0; slow path handles growth
#pragma unroll
  for (int f = 0; f < 4; ++f) o[f] = 0.f;
  ol = 0.f;

  union { short8 s; bf16x8 b; } oneu;
#pragma unroll
  for (int j = 0; j < 8; ++j) oneu.s[j] = 0x3F80;  // bf16 1.0
  const bf16x8 onesf = oneu.b;

  // gload staging: LDS slot sigma holds content chunk (r = sigma>>3, h = (sigma&7)^(r&7))
  // (chunk-XOR swizzle is involutive -> pre-swizzle the global source, LDS stays linear)
  const int sA = tid, sB = tid + 256;
  const int rA = sA >> 3, hA = (sA & 7) ^ (rA & 7);
  const int rB = sB >> 3, hB = (sB & 7) ^ (rB & 7);
  const unsigned short* kSrcA = Kh + rA * 64 + hA * 8;
  const unsigned short* kSrcB = Kh + rB * 64 + hB * 8;
  const unsigned short* vSrcA = Vh + (size_t)rA * 2048 + hA * 8;
  const unsigned short* vSrcB = Vh + (size_t)rB * 2048 + hB * 8;
  const int ldsA = w * 64 * 8;           // wave-uniform LDS element offsets
  const int ldsB = (256 + w * 64) * 8;

  const int sw = l16 & 7;
  const int ntiles = qt + 1;

  // prologue: tile 0 -> buffer 0
  gload16(kSrcA, &Ks[0][ldsA]);
  gload16(kSrcB, &Ks[0][ldsB]);
  gload16(vSrcA, &Vs[0][ldsA]);
  gload16(vSrcB, &Vs[0][ldsB]);
  __syncthreads();

  for (int t = 0; t < ntiles; ++t) {
    const int kv0 = t * 64;
    const int cur = t & 1;
    if (t + 1 < ntiles) {  // prefetch next tile into other buffer (DMA, lands by barrier)
      const int nk = kv0 + 64;
      gload16(kSrcA + (size_t)nk * 64, &Ks[cur ^ 1][ldsA]);
      gload16(kSrcB + (size_t)nk * 64, &Ks[cur ^ 1][ldsB]);
      gload16(vSrcA + nk, &Vs[cur ^ 1][ldsA]);
      gload16(vSrcB + nk, &Vs[cur ^ 1][ldsB]);
    }

    const unsigned short* Kb = Ks[cur];
    const unsigned short* Vb = Vs[cur];

    // QK^T: S[q=lh*4+r][kv=tt*16+l16]  (log2-scaled)
    f32x4 s[4];
#pragma unroll
    for (int tt = 0; tt < 4; ++tt) {
      const unsigned short* krow = Kb + (tt * 16 + l16) * 64;
      bf16x8 kf0 = *(const bf16x8*)(krow + ((lh ^ sw) * 8));
      bf16x8 kf1 = *(const bf16x8*)(krow + (((lh + 4) ^ sw) * 8));
      f32x4 a = {0.f, 0.f, 0.f, 0.f};
      a = MFMA16(qf0, kf0, a);
      a = MFMA16(qf1, kf1, a);
      s[tt] = a;
    }

    if (kv0 + 63 > wqb) {  // causal mask (diag tiles only)
#pragma unroll
      for (int tt = 0; tt < 4; ++tt) {
        int col = kv0 + tt * 16 + l16;
#pragma unroll
        for (int r = 0; r < 4; ++r)
          if (col > wqb + lh * 4 + r) s[tt][r] = -__builtin_inff();
      }
    }

    // defer-max: fast path has no shuffles, no rescale
    float pmax[4];
#pragma unroll
    for (int r = 0; r < 4; ++r)
      pmax[r] = fmaxf(fmaxf(s[0][r], s[1][r]), fmaxf(s[2][r], s[3][r]));
    int ok = (pmax[0] <= mreg[0] + 8.f) && (pmax[1] <= mreg[1] + 8.f) &&
             (pmax[2] <= mreg[2] + 8.f) && (pmax[3] <= mreg[3] + 8.f);
    if (!__all(ok)) {  // slow path: full row-max reduce + rescale O and L
#pragma unroll
      for (int r = 0; r < 4; ++r) {
        float t0 = pmax[r];
        t0 = fmaxf(t0, __shfl_xor(t0, 1));
        t0 = fmaxf(t0, __shfl_xor(t0, 2));
        t0 = fmaxf(t0, __shfl_xor(t0, 4));
        t0 = fmaxf(t0, __shfl_xor(t0, 8));
        float mn = fmaxf(mreg[r], t0);
        float esc = exp2f(mreg[r] - mn);
        mreg[r] = mn;
#pragma unroll
        for (int f = 0; f < 4; ++f) o[f][r] *= esc;
        ol[r] *= esc;
      }
    }

    // P = exp2(s - m), truncate to bf16 (bias cancels in O/L ratio), stash in LDS
    unsigned short* Pw = Pl[w];
#pragma unroll
    for (int r = 0; r < 4; ++r) {
      int prow = lh * 4 + r;
      int pbase = prow * 64;
      int px = (prow & 7) << 3;
#pragma unroll
      for (int tt = 0; tt < 4; ++tt) {
        float p = exp2f(s[tt][r] - mreg[r]);
        Pw[pbase + ((tt * 16 + l16) ^ px)] =
            (unsigned short)(__builtin_bit_cast(unsigned int, p) >> 16);
      }
    }
    bf16x8 pf0 = *(const bf16x8*)(Pw + l16 * 64 + ((lh ^ sw) * 8));
    bf16x8 pf1 = *(const bf16x8*)(Pw + l16 * 64 + (((lh + 4) ^ sw) * 8));
#pragma unroll
    for (int f = 0; f < 4; ++f) {
      const unsigned short* vrow = Vb + (f * 16 + l16) * 64;
      bf16x8 vf0 = *(const bf16x8*)(vrow + ((lh ^ sw) * 8));
      bf16x8 vf1 = *(const bf16x8*)(vrow + (((lh + 4) ^ sw) * 8));
      o[f] = MFMA16(pf0, vf0, o[f]);
      o[f] = MFMA16(pf1, vf1, o[f]);
    }
    ol = MFMA16(pf0, onesf, ol);  // row sums via MFMA: L rides the same rescale as O
    ol = MFMA16(pf1, onesf, ol);

    __syncthreads();
  }

  unsigned short* op = Og + (size_t)bb * 2048 * 1024 + (size_t)hh * 64;
#pragma unroll
  for (int f = 0; f < 4; ++f) {
#pragma unroll
    for (int r = 0; r < 4; ++r) {
      int row = wqb + lh * 4 + r;
      op[(size_t)row * 1024 + f * 16 + l16] = f32_bf16(o[f][r] / ol[r]);
    }
  }
}

extern "C" void kernel_launch(void* const* d_in, const int* in_sizes, int n_in,
                              void* d_out, int out_size, void* d_ws, size_t ws_size,
                              hipStream_t stream) {
  const float* x    = (const float*)d_in[0];
  const float* Wqkv = (const float*)d_in[1];
  const float* Wout = (const float*)d_in[2];
  float* out = (float*)d_out;

  char* ws = (char*)d_ws;
  unsigned short* xb  = (unsigned short*)(ws);                              // 8 MB
  unsigned short* wqb = (unsigned short*)(ws + (size_t)8 * 1024 * 1024);    // 6 MB
  unsigned short* wob = (unsigned short*)(ws + (size_t)14 * 1024 * 1024);   // 2 MB
  unsigned short* qkv = (unsigned short*)(ws + (size_t)16 * 1024 * 1024);   // 24 MB
  unsigned short* att = (unsigned short*)(ws + (size_t)40 * 1024 * 1024);   // 8 MB

  cvt_kernel<<<4096, 256, 0, stream>>>(x, xb, 4194304 / 4);
  cvt_kernel<<<3072, 256, 0, stream>>>(Wqkv, wqb, 3145728 / 4);
  cvt_kernel<<<1024, 256, 0, stream>>>(Wout, wob, 1048576 / 4);

  // QKV projection -> Q,K [bh][s][dk] (Q in exp2-space scale); V^T [bh][dk][s]
  gemm_bt<0><<<dim3(24, 32), 256, 0, stream>>>(xb, wqb, (void*)qkv, 4096, 3072, 1024);

  const unsigned short* Qp  = qkv;
  const unsigned short* Kp  = qkv + 4194304;
  const unsigned short* Vtp = qkv + 8388608;
  attn_kernel<<<1024, 256, 0, stream>>>(Qp, Kp, Vtp, att);

  // output projection -> fp32 out
  gemm_bt<1><<<dim3(8, 32), 256, 0, stream>>>(att, wob, (void*)out, 4096, 1024, 1024);
}